// Round 4
// baseline (124.705 us; speedup 1.0000x reference)
//
#include <hip/hip_runtime.h>

// LearnPermutations: K=256 independent 256x256 Sinkhorn normalizations.
// One 1024-thread block per matrix; matrix register-resident (8x8 tile/thread
// as float2[8][4]). Iteration 1 in log2 domain (huge 1/tau dynamic range),
// then scaling-vector Sinkhorn u = rcp(A v), v = rcp(A^T u) with EARLY EXIT
// when max|rowsum-1| < DELTA (error vs full 26 iters bounded by 25*DELTA).

#define KMAT 256
#define DELTA 1e-4f

typedef unsigned uint2_ev __attribute__((ext_vector_type(2)));

__device__ __forceinline__ float fast_exp2(float x) {
#if __has_builtin(__builtin_amdgcn_exp2f)
  return __builtin_amdgcn_exp2f(x);
#else
  return exp2f(x);
#endif
}

__device__ __forceinline__ float fast_log2(float x) {
#if __has_builtin(__builtin_amdgcn_logf)
  return __builtin_amdgcn_logf(x);
#else
  return __log2f(x);
#endif
}

__device__ __forceinline__ float fast_rcp(float x) {
#if __has_builtin(__builtin_amdgcn_rcpf)
  return __builtin_amdgcn_rcpf(x);
#else
  return 1.0f / x;
#endif
}

__device__ __forceinline__ float2 pk_fma(float2 a, float2 b, float2 c) {
  return make_float2(fmaf(a.x, b.x, c.x), fmaf(a.y, b.y, c.y));
}
__device__ __forceinline__ float2 pk_mul(float2 a, float2 b) {
  return make_float2(a.x * b.x, a.y * b.y);
}
__device__ __forceinline__ float2 pk_sub1(float2 a, float s) {
  return make_float2(a.x - s, a.y - s);
}

template <int CTRL>
__device__ __forceinline__ float dpp_movf(float x) {
  return __int_as_float(
      __builtin_amdgcn_update_dpp(0, __float_as_int(x), CTRL, 0xf, 0xf, true));
}

// Reduce over the aligned 32-lane half-group containing this lane.
__device__ __forceinline__ float hgroup_max(float x) {
  x = fmaxf(x, dpp_movf<0x121>(x));
  x = fmaxf(x, dpp_movf<0x122>(x));
  x = fmaxf(x, dpp_movf<0x124>(x));
  x = fmaxf(x, dpp_movf<0x128>(x));
#if __has_builtin(__builtin_amdgcn_permlane16_swap)
  uint2_ev r = __builtin_amdgcn_permlane16_swap(
      (unsigned)__float_as_int(x), (unsigned)__float_as_int(x), false, false);
  return fmaxf(__int_as_float((int)r.x), __int_as_float((int)r.y));
#else
  return fmaxf(x, __shfl_xor(x, 16, 64));
#endif
}

__device__ __forceinline__ float hgroup_sum(float x) {
  x += dpp_movf<0x121>(x);
  x += dpp_movf<0x122>(x);
  x += dpp_movf<0x124>(x);
  x += dpp_movf<0x128>(x);
#if __has_builtin(__builtin_amdgcn_permlane16_swap)
  uint2_ev r = __builtin_amdgcn_permlane16_swap(
      (unsigned)__float_as_int(x), (unsigned)__float_as_int(x), false, false);
  return __int_as_float((int)r.x) + __int_as_float((int)r.y);
#else
  return x + __shfl_xor(x, 16, 64);
#endif
}

__device__ __forceinline__ float x32_max(float x) {
#if __has_builtin(__builtin_amdgcn_permlane32_swap)
  uint2_ev r = __builtin_amdgcn_permlane32_swap(
      (unsigned)__float_as_int(x), (unsigned)__float_as_int(x), false, false);
  return fmaxf(__int_as_float((int)r.x), __int_as_float((int)r.y));
#else
  return fmaxf(x, __shfl_xor(x, 32, 64));
#endif
}

__device__ __forceinline__ float x32_sum(float x) {
#if __has_builtin(__builtin_amdgcn_permlane32_swap)
  uint2_ev r = __builtin_amdgcn_permlane32_swap(
      (unsigned)__float_as_int(x), (unsigned)__float_as_int(x), false, false);
  return __int_as_float((int)r.x) + __int_as_float((int)r.y);
#else
  return x + __shfl_xor(x, 32, 64);
#endif
}

// Gumbel noise + temperature scaling, output in log2 domain.
__device__ __forceinline__ float gumbel_la(float p, float uv, float scale) {
  float lnu = fast_log2(uv + 1e-20f) * 0.69314718056f;
  float g = fast_log2(1e-20f - lnu) * (-0.0069314718056f);
  return (p + g) * scale;
}

__global__ __launch_bounds__(1024, 4) void lp_sinkhorn_kernel(
    const float* __restrict__ plw, const float* __restrict__ uin,
    const int* __restrict__ itp, float* __restrict__ out) {
  const int k = blockIdx.x;
  const int t = threadIdx.x;
  const int br = t >> 5;   // 0..31 : block-row (8 rows each)
  const int bc = t & 31;   // 0..31 : block-col (8 cols each)
  const int wv = t >> 6;   // wave 0..15
  const int lane = t & 63;

  // Pair-slot layout: column pair cp = 4*bc + p lives at slot s = 32*p + bc.
  // float-word index for (col j): 2*s + (j&1) = 64*((j&7)>>1) + 2*(j>>3) + (j&1).
  __shared__ float2 red2[16][132];  // [wave][slot 0..127]; slot128.x = wave dev
  __shared__ float2 colv2[132];     // slots 0..127; word 256 (= [128].x) = flag
  float* fr = (float*)red2;         // wave stride = 264 words
  float* fc = (float*)colv2;

  // ---- schedule parameters from `iterations` (uniform) ----
  double frac = (double)itp[0] * 1e-5;
  frac = frac < 0.0 ? 0.0 : (frac > 1.0 ? 1.0 : frac);
  const int n_iters = (int)(20.0 + frac * 130.0);
  const float tauf = (float)exp2((-3.0 - 4.0 * frac) * 3.3219280948873623);
  const float scale = (float)(1.4426950408889634 / (double)tauf);

  float2 la[8][4];

  // ---- load + gumbel + scale ----
  const float4* p4 = (const float4*)plw + k * 16384;
  const float4* u4 = (const float4*)uin + k * 16384;
#pragma unroll
  for (int i = 0; i < 8; ++i) {
    const int ridx = ((br << 3) + i) * 64 + (bc << 1);
    float4 p0 = p4[ridx];
    float4 p1 = p4[ridx + 1];
    float4 v0 = u4[ridx];
    float4 v1 = u4[ridx + 1];
    la[i][0] = make_float2(gumbel_la(p0.x, v0.x, scale),
                           gumbel_la(p0.y, v0.y, scale));
    la[i][1] = make_float2(gumbel_la(p0.z, v0.z, scale),
                           gumbel_la(p0.w, v0.w, scale));
    la[i][2] = make_float2(gumbel_la(p1.x, v1.x, scale),
                           gumbel_la(p1.y, v1.y, scale));
    la[i][3] = make_float2(gumbel_la(p1.z, v1.z, scale),
                           gumbel_la(p1.w, v1.w, scale));
  }

  const int pb = (lane < 32) ? 0 : 2;  // which pairs this half-wave writes
  const int s2 = 64 * ((t & 7) >> 1) + 2 * (t >> 3) + (t & 1);  // tree word idx

  // ======== iteration 1: LOG domain (row then col), ends linear ========
#pragma unroll
  for (int i = 0; i < 8; ++i) {
    float m = fmaxf(la[i][0].x, la[i][0].y);
#pragma unroll
    for (int p = 1; p < 4; ++p) m = fmaxf(m, fmaxf(la[i][p].x, la[i][p].y));
    m = hgroup_max(m);
    float s = 0.f;
#pragma unroll
    for (int p = 0; p < 4; ++p)
      s += fast_exp2(la[i][p].x - m) + fast_exp2(la[i][p].y - m);
    s = hgroup_sum(s);
    const float lse = m + fast_log2(s);
#pragma unroll
    for (int p = 0; p < 4; ++p) la[i][p] = pk_sub1(la[i][p], lse);
  }

  {  // col pass in log domain; convert to linear at the end
    float2 cm[4];
#pragma unroll
    for (int p = 0; p < 4; ++p) {
      float2 m = la[0][p];
#pragma unroll
      for (int i = 1; i < 8; ++i)
        m = make_float2(fmaxf(m.x, la[i][p].x), fmaxf(m.y, la[i][p].y));
      cm[p] = make_float2(x32_max(m.x), x32_max(m.y));
    }
    red2[wv][32 * pb + bc] = cm[pb];
    red2[wv][32 * pb + 32 + bc] = cm[pb + 1];
    __syncthreads();

    float keepm = 0.f;
    if (t < 256) {
      float v = fr[s2];
#pragma unroll
      for (int w = 1; w < 16; ++w) v = fmaxf(v, fr[w * 264 + s2]);
      keepm = v;
      fc[s2] = v;
    }
    if (t == 0) fc[256] = 1e9f;  // init convergence flag
    __syncthreads();

    float2 cs[4];
#pragma unroll
    for (int p = 0; p < 4; ++p) {
      const float2 mj = colv2[32 * p + bc];
      float2 s = make_float2(0.f, 0.f);
#pragma unroll
      for (int i = 0; i < 8; ++i)
        s = make_float2(s.x + fast_exp2(la[i][p].x - mj.x),
                        s.y + fast_exp2(la[i][p].y - mj.y));
      cs[p] = make_float2(x32_sum(s.x), x32_sum(s.y));
    }
    red2[wv][32 * pb + bc] = cs[pb];
    red2[wv][32 * pb + 32 + bc] = cs[pb + 1];
    __syncthreads();

    if (t < 256) {
      float v = fr[s2];
#pragma unroll
      for (int w = 1; w < 16; ++w) v += fr[w * 264 + s2];
      fc[s2] = keepm + fast_log2(v);
    }
    __syncthreads();

    // convert to linear: a = exp2(la - col_lse); colsums(a) == 1
#pragma unroll
    for (int p = 0; p < 4; ++p) {
      const float2 lse = colv2[32 * p + bc];
#pragma unroll
      for (int i = 0; i < 8; ++i)
        la[i][p] = make_float2(fast_exp2(la[i][p].x - lse.x),
                               fast_exp2(la[i][p].y - lse.y));
    }
  }

  // ======== iterations 2..n: scaling-vector Sinkhorn with early exit ======
  float uo[8] = {1.f, 1.f, 1.f, 1.f, 1.f, 1.f, 1.f, 1.f};
  float2 v2[4] = {make_float2(1.f, 1.f), make_float2(1.f, 1.f),
                  make_float2(1.f, 1.f), make_float2(1.f, 1.f)};
  float flag = 1e9f;

  for (int iter = 1; iter < n_iters; ++iter) {
    if (flag < DELTA) break;  // block-uniform; |ours - ref| <= 25*DELTA

    // row: u_i = rcp( sum_j a_ij * v_j ); track max |rowsum - 1|
    float dl = 0.f;
#pragma unroll
    for (int i = 0; i < 8; ++i) {
      float2 a0 = pk_mul(la[i][0], v2[0]);
      float2 a1 = pk_mul(la[i][1], v2[1]);
      a0 = pk_fma(la[i][2], v2[2], a0);
      a1 = pk_fma(la[i][3], v2[3], a1);
      const float s = hgroup_sum((a0.x + a1.x) + (a0.y + a1.y));
      uo[i] = fast_rcp(s);
      dl = fmaxf(dl, fabsf(s - 1.0f));
    }
    const float dev = x32_max(dl);

    // col partials: cs_j = sum_{i in my rows} a_ij * u_i
    float2 cs[4] = {make_float2(0.f, 0.f), make_float2(0.f, 0.f),
                    make_float2(0.f, 0.f), make_float2(0.f, 0.f)};
#pragma unroll
    for (int i = 0; i < 8; ++i) {
      const float2 ub = make_float2(uo[i], uo[i]);
#pragma unroll
      for (int p = 0; p < 4; ++p) cs[p] = pk_fma(la[i][p], ub, cs[p]);
    }
#pragma unroll
    for (int p = 0; p < 4; ++p)
      cs[p] = make_float2(x32_sum(cs[p].x), x32_sum(cs[p].y));

    red2[wv][32 * pb + bc] = cs[pb];
    red2[wv][32 * pb + 32 + bc] = cs[pb + 1];
    if (lane == 0) red2[wv][128].x = dev;
    __syncthreads();

    if (t < 256) {
      float v = fr[s2];
#pragma unroll
      for (int w = 1; w < 16; ++w) v += fr[w * 264 + s2];
      fc[s2] = fast_rcp(v);
    }
    if (t == 0) {
      float d = fr[256];
#pragma unroll
      for (int w = 1; w < 16; ++w) d = fmaxf(d, fr[w * 264 + 256]);
      fc[256] = d;
    }
    __syncthreads();

#pragma unroll
    for (int p = 0; p < 4; ++p) v2[p] = colv2[32 * p + bc];
    flag = fc[256];
    // next iteration's post-write __syncthreads protects colv2/red2 hazards
  }

  // ---- output: out_ij = a_ij * u_i * v_j ----
  float4* o4 = (float4*)out + k * 16384;
#pragma unroll
  for (int i = 0; i < 8; ++i) {
    const int ridx = ((br << 3) + i) * 64 + (bc << 1);
    const float2 ub = make_float2(uo[i], uo[i]);
    float2 r0 = pk_mul(pk_mul(la[i][0], ub), v2[0]);
    float2 r1 = pk_mul(pk_mul(la[i][1], ub), v2[1]);
    float2 r2 = pk_mul(pk_mul(la[i][2], ub), v2[2]);
    float2 r3 = pk_mul(pk_mul(la[i][3], ub), v2[3]);
    float4 a, b;
    a.x = r0.x; a.y = r0.y; a.z = r1.x; a.w = r1.y;
    b.x = r2.x; b.y = r2.y; b.z = r3.x; b.w = r3.y;
    o4[ridx] = a;
    o4[ridx + 1] = b;
  }
}

extern "C" void kernel_launch(void* const* d_in, const int* in_sizes, int n_in,
                              void* d_out, int out_size, void* d_ws,
                              size_t ws_size, hipStream_t stream) {
  const float* plw = (const float*)d_in[0];
  const float* u = (const float*)d_in[1];
  const int* iters = (const int*)d_in[2];
  float* out = (float*)d_out;
  (void)in_sizes; (void)n_in; (void)out_size; (void)d_ws; (void)ws_size;
  lp_sinkhorn_kernel<<<dim3(KMAT), dim3(1024), 0, stream>>>(plw, u, iters, out);
}

// Round 5
// 99.966 us; speedup vs baseline: 1.2475x; 1.2475x over previous
//
#include <hip/hip_runtime.h>

// LearnPermutations: K=256 independent 256x256 Sinkhorn normalizations.
// One 1024-thread block per matrix; matrix register-resident (8x8 tile/thread
// as float2[8][4], forced v_pk_* packed fp32). Iteration 1 in log2 domain
// (huge 1/tau dynamic range), then scaling-vector Sinkhorn:
// u = rcp(A v), v = rcp(A^T u); final out = a_ij * u_i * v_j.

#define KMAT 256

typedef unsigned uint2_ev __attribute__((ext_vector_type(2)));

__device__ __forceinline__ float fast_exp2(float x) {
#if __has_builtin(__builtin_amdgcn_exp2f)
  return __builtin_amdgcn_exp2f(x);
#else
  return exp2f(x);
#endif
}

__device__ __forceinline__ float fast_log2(float x) {
#if __has_builtin(__builtin_amdgcn_logf)
  return __builtin_amdgcn_logf(x);
#else
  return __log2f(x);
#endif
}

__device__ __forceinline__ float fast_rcp(float x) {
#if __has_builtin(__builtin_amdgcn_rcpf)
  return __builtin_amdgcn_rcpf(x);
#else
  return 1.0f / x;
#endif
}

// Packed fp32 ops (VOP3P) — hipcc does not reliably fuse float2 math into
// v_pk_*; force it. (asm non-volatile: pure, schedulable, CSE-able.)
__device__ __forceinline__ float2 pk_fma(float2 a, float2 b, float2 c) {
  float2 d;
  asm("v_pk_fma_f32 %0, %1, %2, %3" : "=v"(d) : "v"(a), "v"(b), "v"(c));
  return d;
}
__device__ __forceinline__ float2 pk_mul(float2 a, float2 b) {
  float2 d;
  asm("v_pk_mul_f32 %0, %1, %2" : "=v"(d) : "v"(a), "v"(b));
  return d;
}
__device__ __forceinline__ float2 pk_add(float2 a, float2 b) {
  float2 d;
  asm("v_pk_add_f32 %0, %1, %2" : "=v"(d) : "v"(a), "v"(b));
  return d;
}
__device__ __forceinline__ float2 pk_sub1(float2 a, float s) {
  return make_float2(a.x - s, a.y - s);
}

template <int CTRL>
__device__ __forceinline__ float dpp_movf(float x) {
  return __int_as_float(
      __builtin_amdgcn_update_dpp(0, __float_as_int(x), CTRL, 0xf, 0xf, true));
}

// Reduce over the aligned 32-lane half-group containing this lane.
__device__ __forceinline__ float hgroup_max(float x) {
  x = fmaxf(x, dpp_movf<0x121>(x));
  x = fmaxf(x, dpp_movf<0x122>(x));
  x = fmaxf(x, dpp_movf<0x124>(x));
  x = fmaxf(x, dpp_movf<0x128>(x));
#if __has_builtin(__builtin_amdgcn_permlane16_swap)
  uint2_ev r = __builtin_amdgcn_permlane16_swap(
      (unsigned)__float_as_int(x), (unsigned)__float_as_int(x), false, false);
  return fmaxf(__int_as_float((int)r.x), __int_as_float((int)r.y));
#else
  return fmaxf(x, __shfl_xor(x, 16, 64));
#endif
}

__device__ __forceinline__ float hgroup_sum(float x) {
  x += dpp_movf<0x121>(x);
  x += dpp_movf<0x122>(x);
  x += dpp_movf<0x124>(x);
  x += dpp_movf<0x128>(x);
#if __has_builtin(__builtin_amdgcn_permlane16_swap)
  uint2_ev r = __builtin_amdgcn_permlane16_swap(
      (unsigned)__float_as_int(x), (unsigned)__float_as_int(x), false, false);
  return __int_as_float((int)r.x) + __int_as_float((int)r.y);
#else
  return x + __shfl_xor(x, 16, 64);
#endif
}

__device__ __forceinline__ float x32_max(float x) {
#if __has_builtin(__builtin_amdgcn_permlane32_swap)
  uint2_ev r = __builtin_amdgcn_permlane32_swap(
      (unsigned)__float_as_int(x), (unsigned)__float_as_int(x), false, false);
  return fmaxf(__int_as_float((int)r.x), __int_as_float((int)r.y));
#else
  return fmaxf(x, __shfl_xor(x, 32, 64));
#endif
}

__device__ __forceinline__ float x32_sum(float x) {
#if __has_builtin(__builtin_amdgcn_permlane32_swap)
  uint2_ev r = __builtin_amdgcn_permlane32_swap(
      (unsigned)__float_as_int(x), (unsigned)__float_as_int(x), false, false);
  return __int_as_float((int)r.x) + __int_as_float((int)r.y);
#else
  return x + __shfl_xor(x, 32, 64);
#endif
}

// Gumbel noise + temperature scaling, output in log2 domain.
__device__ __forceinline__ float gumbel_la(float p, float uv, float scale) {
  float lnu = fast_log2(uv + 1e-20f) * 0.69314718056f;
  float g = fast_log2(1e-20f - lnu) * (-0.0069314718056f);
  return (p + g) * scale;
}

__global__ __launch_bounds__(1024, 4) void lp_sinkhorn_kernel(
    const float* __restrict__ plw, const float* __restrict__ uin,
    const int* __restrict__ itp, float* __restrict__ out) {
  const int k = blockIdx.x;
  const int t = threadIdx.x;
  const int br = t >> 5;   // 0..31 : block-row (8 rows each)
  const int bc = t & 31;   // 0..31 : block-col (8 cols each)
  const int wv = t >> 6;   // wave 0..15
  const int lane = t & 63;

  // R3 layout (verified conflict-free): column c = 8*bc + j lives at slot
  // s(c) = bc + 32*j. Tree reads stride 256 between waves -> bank = s % 32.
  __shared__ float red[16 * 256];
  __shared__ float colv[256];

  // ---- schedule parameters from `iterations` (uniform) ----
  double frac = (double)itp[0] * 1e-5;
  frac = frac < 0.0 ? 0.0 : (frac > 1.0 ? 1.0 : frac);
  const int n_iters = (int)(20.0 + frac * 130.0);
  const float tauf = (float)exp2((-3.0 - 4.0 * frac) * 3.3219280948873623);
  const float scale = (float)(1.4426950408889634 / (double)tauf);

  float2 la[8][4];

  // ---- load + gumbel + scale ----
  const float4* p4 = (const float4*)plw + k * 16384;
  const float4* u4 = (const float4*)uin + k * 16384;
#pragma unroll
  for (int i = 0; i < 8; ++i) {
    const int ridx = ((br << 3) + i) * 64 + (bc << 1);
    float4 p0 = p4[ridx];
    float4 p1 = p4[ridx + 1];
    float4 v0 = u4[ridx];
    float4 v1 = u4[ridx + 1];
    la[i][0] = make_float2(gumbel_la(p0.x, v0.x, scale),
                           gumbel_la(p0.y, v0.y, scale));
    la[i][1] = make_float2(gumbel_la(p0.z, v0.z, scale),
                           gumbel_la(p0.w, v0.w, scale));
    la[i][2] = make_float2(gumbel_la(p1.x, v1.x, scale),
                           gumbel_la(p1.y, v1.y, scale));
    la[i][3] = make_float2(gumbel_la(p1.z, v1.z, scale),
                           gumbel_la(p1.w, v1.w, scale));
  }

  // jlo: which 4 columns (of this thread's 8) this lane-half writes to LDS.
  const int jlo = (lane < 32) ? 0 : 4;

  // ======== iteration 1: LOG domain (row then col), ends linear ========
#pragma unroll
  for (int i = 0; i < 8; ++i) {
    float m = fmaxf(la[i][0].x, la[i][0].y);
#pragma unroll
    for (int p = 1; p < 4; ++p) m = fmaxf(m, fmaxf(la[i][p].x, la[i][p].y));
    m = hgroup_max(m);
    float s = 0.f;
#pragma unroll
    for (int p = 0; p < 4; ++p)
      s += fast_exp2(la[i][p].x - m) + fast_exp2(la[i][p].y - m);
    s = hgroup_sum(s);
    const float lse = m + fast_log2(s);
#pragma unroll
    for (int p = 0; p < 4; ++p) la[i][p] = pk_sub1(la[i][p], lse);
  }

  {  // col pass in log domain; convert to linear at the end
    float cm[8];
#pragma unroll
    for (int p = 0; p < 4; ++p) {
      float2 m = la[0][p];
#pragma unroll
      for (int i = 1; i < 8; ++i)
        m = make_float2(fmaxf(m.x, la[i][p].x), fmaxf(m.y, la[i][p].y));
      cm[2 * p] = x32_max(m.x);
      cm[2 * p + 1] = x32_max(m.y);
    }
#pragma unroll
    for (int j = 0; j < 4; ++j) red[wv * 256 + bc + 32 * (jlo + j)] = cm[jlo + j];
    __syncthreads();

    float keepm = 0.f;
    if (t < 256) {
      float v = red[t];
#pragma unroll
      for (int w = 1; w < 16; ++w) v = fmaxf(v, red[w * 256 + t]);
      keepm = v;
      colv[t] = v;
    }
    __syncthreads();

    float cs[8];
#pragma unroll
    for (int p = 0; p < 4; ++p) {
      const float2 mj = make_float2(colv[bc + 32 * (2 * p)],
                                    colv[bc + 32 * (2 * p + 1)]);
      float2 s = make_float2(0.f, 0.f);
#pragma unroll
      for (int i = 0; i < 8; ++i)
        s = make_float2(s.x + fast_exp2(la[i][p].x - mj.x),
                        s.y + fast_exp2(la[i][p].y - mj.y));
      cs[2 * p] = x32_sum(s.x);
      cs[2 * p + 1] = x32_sum(s.y);
    }
    __syncthreads();  // protect colv before overwrite
#pragma unroll
    for (int j = 0; j < 4; ++j) red[wv * 256 + bc + 32 * (jlo + j)] = cs[jlo + j];
    __syncthreads();

    if (t < 256) {
      float v = red[t];
#pragma unroll
      for (int w = 1; w < 16; ++w) v += red[w * 256 + t];
      colv[t] = keepm + fast_log2(v);
    }
    __syncthreads();

    // convert to linear: a = exp2(la - col_lse); colsums(a) == 1
#pragma unroll
    for (int p = 0; p < 4; ++p) {
      const float2 lse = make_float2(colv[bc + 32 * (2 * p)],
                                     colv[bc + 32 * (2 * p + 1)]);
#pragma unroll
      for (int i = 0; i < 8; ++i)
        la[i][p] = make_float2(fast_exp2(la[i][p].x - lse.x),
                               fast_exp2(la[i][p].y - lse.y));
    }
  }

  // ======== iterations 2..n: scaling-vector Sinkhorn ========
  // u = rcp(A v); v = rcp(A^T u). Matrix registers read-only; all sums in
  // [1/256, 256] (colsums start at 1) -> rcp safe.
  float uo[8] = {1.f, 1.f, 1.f, 1.f, 1.f, 1.f, 1.f, 1.f};
  float2 v2[4] = {make_float2(1.f, 1.f), make_float2(1.f, 1.f),
                  make_float2(1.f, 1.f), make_float2(1.f, 1.f)};

  for (int iter = 1; iter < n_iters; ++iter) {
    // row: u_i = rcp( sum_j a_ij * v_j )
#pragma unroll
    for (int i = 0; i < 8; ++i) {
      float2 a0 = pk_mul(la[i][0], v2[0]);
      float2 a1 = pk_mul(la[i][1], v2[1]);
      a0 = pk_fma(la[i][2], v2[2], a0);
      a1 = pk_fma(la[i][3], v2[3], a1);
      a0 = pk_add(a0, a1);
      const float s = hgroup_sum(a0.x + a0.y);
      uo[i] = fast_rcp(s);
    }

    // col partials: cs_j = sum_{i in my rows} a_ij * u_i
    float2 cs2[4] = {make_float2(0.f, 0.f), make_float2(0.f, 0.f),
                     make_float2(0.f, 0.f), make_float2(0.f, 0.f)};
#pragma unroll
    for (int i = 0; i < 8; ++i) {
      const float2 ub = make_float2(uo[i], uo[i]);
#pragma unroll
      for (int p = 0; p < 4; ++p) cs2[p] = pk_fma(la[i][p], ub, cs2[p]);
    }
    float cs[8];
#pragma unroll
    for (int p = 0; p < 4; ++p) {
      cs[2 * p] = x32_sum(cs2[p].x);
      cs[2 * p + 1] = x32_sum(cs2[p].y);
    }
#pragma unroll
    for (int j = 0; j < 4; ++j) red[wv * 256 + bc + 32 * (jlo + j)] = cs[jlo + j];
    __syncthreads();

    // tree over 16 wave-partials: 128 threads x float2 (b64, conflict-free)
    if (t < 128) {
      const float2* r2 = (const float2*)red;
      float2 v = r2[t];
#pragma unroll
      for (int w = 1; w < 16; ++w) v = pk_add(v, r2[w * 128 + t]);
      float2* c2 = (float2*)colv;
      c2[t] = make_float2(fast_rcp(v.x), fast_rcp(v.y));
    }
    __syncthreads();

#pragma unroll
    for (int p = 0; p < 4; ++p)
      v2[p] = make_float2(colv[bc + 32 * (2 * p)],
                          colv[bc + 32 * (2 * p + 1)]);
    // next iteration's post-write __syncthreads protects colv/red hazards
  }

  // ---- output: out_ij = a_ij * u_i * v_j ----
  float4* o4 = (float4*)out + k * 16384;
#pragma unroll
  for (int i = 0; i < 8; ++i) {
    const int ridx = ((br << 3) + i) * 64 + (bc << 1);
    const float2 ub = make_float2(uo[i], uo[i]);
    float2 r0 = pk_mul(pk_mul(la[i][0], ub), v2[0]);
    float2 r1 = pk_mul(pk_mul(la[i][1], ub), v2[1]);
    float2 r2 = pk_mul(pk_mul(la[i][2], ub), v2[2]);
    float2 r3 = pk_mul(pk_mul(la[i][3], ub), v2[3]);
    float4 a, b;
    a.x = r0.x; a.y = r0.y; a.z = r1.x; a.w = r1.y;
    b.x = r2.x; b.y = r2.y; b.z = r3.x; b.w = r3.y;
    o4[ridx] = a;
    o4[ridx + 1] = b;
  }
}

extern "C" void kernel_launch(void* const* d_in, const int* in_sizes, int n_in,
                              void* d_out, int out_size, void* d_ws,
                              size_t ws_size, hipStream_t stream) {
  const float* plw = (const float*)d_in[0];
  const float* u = (const float*)d_in[1];
  const int* iters = (const int*)d_in[2];
  float* out = (float*)d_out;
  (void)in_sizes; (void)n_in; (void)out_size; (void)d_ws; (void)ws_size;
  lp_sinkhorn_kernel<<<dim3(KMAT), dim3(1024), 0, stream>>>(plw, u, iters, out);
}

// Round 6
// 91.317 us; speedup vs baseline: 1.3656x; 1.0947x over previous
//
#include <hip/hip_runtime.h>

// LearnPermutations: K=256 independent 256x256 Sinkhorn normalizations.
// One 1024-thread block per matrix; matrix register-resident (8x8 tile/thread
// as float2[8][4]). Iteration 1 in log2 domain (huge 1/tau range), then
// scaling-vector Sinkhorn u = rcp(A v), v = rcp(A^T u).
// This round: amdgpu_waves_per_eu(4,4) to unlock 128 arch VGPRs (kill AGPR
// round-trips on la), and a distributed all-wave column tree (32 half-wave
// partials, padded stride, quad-DPP finish) replacing the 2-wave tree +
// per-thread x32_sum.

#define KMAT 256
#define RSTRIDE 264  // 256 + 8: rotates LDS bank by 8 per row-group

typedef unsigned uint2_ev __attribute__((ext_vector_type(2)));

__device__ __forceinline__ float fast_exp2(float x) {
#if __has_builtin(__builtin_amdgcn_exp2f)
  return __builtin_amdgcn_exp2f(x);
#else
  return exp2f(x);
#endif
}

__device__ __forceinline__ float fast_log2(float x) {
#if __has_builtin(__builtin_amdgcn_logf)
  return __builtin_amdgcn_logf(x);
#else
  return __log2f(x);
#endif
}

__device__ __forceinline__ float fast_rcp(float x) {
#if __has_builtin(__builtin_amdgcn_rcpf)
  return __builtin_amdgcn_rcpf(x);
#else
  return 1.0f / x;
#endif
}

template <int CTRL>
__device__ __forceinline__ float dpp_movf(float x) {
  return __int_as_float(
      __builtin_amdgcn_update_dpp(0, __float_as_int(x), CTRL, 0xf, 0xf, true));
}

// Reduce over the aligned 32-lane half-group containing this lane.
__device__ __forceinline__ float hgroup_max(float x) {
  x = fmaxf(x, dpp_movf<0x121>(x));  // row_ror:1
  x = fmaxf(x, dpp_movf<0x122>(x));  // row_ror:2
  x = fmaxf(x, dpp_movf<0x124>(x));  // row_ror:4
  x = fmaxf(x, dpp_movf<0x128>(x));  // row_ror:8
#if __has_builtin(__builtin_amdgcn_permlane16_swap)
  uint2_ev r = __builtin_amdgcn_permlane16_swap(
      (unsigned)__float_as_int(x), (unsigned)__float_as_int(x), false, false);
  return fmaxf(__int_as_float((int)r.x), __int_as_float((int)r.y));
#else
  return fmaxf(x, __shfl_xor(x, 16, 64));
#endif
}

__device__ __forceinline__ float hgroup_sum(float x) {
  x += dpp_movf<0x121>(x);
  x += dpp_movf<0x122>(x);
  x += dpp_movf<0x124>(x);
  x += dpp_movf<0x128>(x);
#if __has_builtin(__builtin_amdgcn_permlane16_swap)
  uint2_ev r = __builtin_amdgcn_permlane16_swap(
      (unsigned)__float_as_int(x), (unsigned)__float_as_int(x), false, false);
  return __int_as_float((int)r.x) + __int_as_float((int)r.y);
#else
  return x + __shfl_xor(x, 16, 64);
#endif
}

// Gumbel noise + temperature scaling, output in log2 domain.
__device__ __forceinline__ float gumbel_la(float p, float uv, float scale) {
  float lnu = fast_log2(uv + 1e-20f) * 0.69314718056f;
  float g = fast_log2(1e-20f - lnu) * (-0.0069314718056f);
  return (p + g) * scale;
}

__global__ __launch_bounds__(1024)
__attribute__((amdgpu_waves_per_eu(4, 4)))
void lp_sinkhorn_kernel(
    const float* __restrict__ plw, const float* __restrict__ uin,
    const int* __restrict__ itp, float* __restrict__ out) {
  const int k = blockIdx.x;
  const int t = threadIdx.x;
  const int br = t >> 5;   // 0..31 : half-wave row-group (8 rows each)
  const int bc = t & 31;   // 0..31 : col-group (8 cols each)
  const int wv = t >> 6;   // wave 0..15
  const int lane = t & 63;

  // Column c = 8*bc + j lives at slot s(c) = bc + 32*j (banks: bc, 2-way free).
  // red row-group stride RSTRIDE=264 rotates banks by 8 per group so the
  // distributed tree's strided reads are <=2-way.
  __shared__ float red[32 * RSTRIDE];
  __shared__ float colv[256];

  const int rbase = br * RSTRIDE + bc;        // writer base (this thread)
  const int slot = 16 * wv + (lane >> 2);     // tree: slot owned by this lane
  const int q = lane & 3;                     // tree: partial-quarter index

  // ---- schedule parameters from `iterations` (uniform) ----
  double frac = (double)itp[0] * 1e-5;
  frac = frac < 0.0 ? 0.0 : (frac > 1.0 ? 1.0 : frac);
  const int n_iters = (int)(20.0 + frac * 130.0);
  const float tauf = (float)exp2((-3.0 - 4.0 * frac) * 3.3219280948873623);
  const float scale = (float)(1.4426950408889634 / (double)tauf);

  float2 la[8][4];

  // ---- load + gumbel + scale ----
  const float4* p4 = (const float4*)plw + k * 16384;
  const float4* u4 = (const float4*)uin + k * 16384;
#pragma unroll
  for (int i = 0; i < 8; ++i) {
    const int ridx = ((br << 3) + i) * 64 + (bc << 1);
    float4 p0 = p4[ridx];
    float4 p1 = p4[ridx + 1];
    float4 v0 = u4[ridx];
    float4 v1 = u4[ridx + 1];
    la[i][0] = make_float2(gumbel_la(p0.x, v0.x, scale),
                           gumbel_la(p0.y, v0.y, scale));
    la[i][1] = make_float2(gumbel_la(p0.z, v0.z, scale),
                           gumbel_la(p0.w, v0.w, scale));
    la[i][2] = make_float2(gumbel_la(p1.x, v1.x, scale),
                           gumbel_la(p1.y, v1.y, scale));
    la[i][3] = make_float2(gumbel_la(p1.z, v1.z, scale),
                           gumbel_la(p1.w, v1.w, scale));
  }

  // ======== iteration 1: LOG domain (row then col), ends linear ========
#pragma unroll
  for (int i = 0; i < 8; ++i) {
    float m = fmaxf(la[i][0].x, la[i][0].y);
#pragma unroll
    for (int p = 1; p < 4; ++p) m = fmaxf(m, fmaxf(la[i][p].x, la[i][p].y));
    m = hgroup_max(m);
    float s = 0.f;
#pragma unroll
    for (int p = 0; p < 4; ++p)
      s += fast_exp2(la[i][p].x - m) + fast_exp2(la[i][p].y - m);
    s = hgroup_sum(s);
    const float lse = m + fast_log2(s);
#pragma unroll
    for (int p = 0; p < 4; ++p)
      la[i][p] = make_float2(la[i][p].x - lse, la[i][p].y - lse);
  }

  {  // col pass in log domain; convert to linear at the end
    // local per-thread col maxes (over this thread's 8 rows), no x32
#pragma unroll
    for (int p = 0; p < 4; ++p) {
      float2 m = la[0][p];
#pragma unroll
      for (int i = 1; i < 8; ++i)
        m = make_float2(fmaxf(m.x, la[i][p].x), fmaxf(m.y, la[i][p].y));
      red[rbase + 32 * (2 * p)] = m.x;
      red[rbase + 32 * (2 * p + 1)] = m.y;
    }
    __syncthreads();

    {  // distributed max-tree: all 16 waves, 8 reads + quad-DPP
      float v = red[q * RSTRIDE + slot];
#pragma unroll
      for (int m = 1; m < 8; ++m)
        v = fmaxf(v, red[(q + 4 * m) * RSTRIDE + slot]);
      v = fmaxf(v, dpp_movf<0xB1>(v));  // quad_perm xor1
      v = fmaxf(v, dpp_movf<0x4E>(v));  // quad_perm xor2
      if (q == 0) colv[slot] = v;
    }
    __syncthreads();

    // exp partial sums against global col max (per-thread, no x32)
#pragma unroll
    for (int p = 0; p < 4; ++p) {
      const float2 mj = make_float2(colv[bc + 32 * (2 * p)],
                                    colv[bc + 32 * (2 * p + 1)]);
      float2 s = make_float2(0.f, 0.f);
#pragma unroll
      for (int i = 0; i < 8; ++i)
        s = make_float2(s.x + fast_exp2(la[i][p].x - mj.x),
                        s.y + fast_exp2(la[i][p].y - mj.y));
      red[rbase + 32 * (2 * p)] = s.x;
      red[rbase + 32 * (2 * p + 1)] = s.y;
    }
    __syncthreads();

    {  // distributed sum-tree; lse = colmax + log2(sum)
      float v = red[q * RSTRIDE + slot];
#pragma unroll
      for (int m = 1; m < 8; ++m) v += red[(q + 4 * m) * RSTRIDE + slot];
      v += dpp_movf<0xB1>(v);
      v += dpp_movf<0x4E>(v);
      const float lse = colv[slot] + fast_log2(v);
      if (q == 0) colv[slot] = lse;
    }
    __syncthreads();

    // convert to linear: a = exp2(la - col_lse); colsums(a) == 1
#pragma unroll
    for (int p = 0; p < 4; ++p) {
      const float2 lse = make_float2(colv[bc + 32 * (2 * p)],
                                     colv[bc + 32 * (2 * p + 1)]);
#pragma unroll
      for (int i = 0; i < 8; ++i)
        la[i][p] = make_float2(fast_exp2(la[i][p].x - lse.x),
                               fast_exp2(la[i][p].y - lse.y));
    }
  }

  // ======== iterations 2..n: scaling-vector Sinkhorn ========
  // u = rcp(A v); v = rcp(A^T u). Matrix registers read-only; all sums in
  // [1/256, 256] (colsums start at 1) -> rcp safe.
  float uo[8] = {1.f, 1.f, 1.f, 1.f, 1.f, 1.f, 1.f, 1.f};
  float2 v2[4] = {make_float2(1.f, 1.f), make_float2(1.f, 1.f),
                  make_float2(1.f, 1.f), make_float2(1.f, 1.f)};

  for (int iter = 1; iter < n_iters; ++iter) {
    // row: u_i = rcp( sum_j a_ij * v_j )   (in-wave only)
#pragma unroll
    for (int i = 0; i < 8; ++i) {
      float2 a0 = make_float2(la[i][0].x * v2[0].x, la[i][0].y * v2[0].y);
      float2 a1 = make_float2(la[i][1].x * v2[1].x, la[i][1].y * v2[1].y);
      a0 = make_float2(fmaf(la[i][2].x, v2[2].x, a0.x),
                       fmaf(la[i][2].y, v2[2].y, a0.y));
      a1 = make_float2(fmaf(la[i][3].x, v2[3].x, a1.x),
                       fmaf(la[i][3].y, v2[3].y, a1.y));
      const float s = hgroup_sum((a0.x + a1.x) + (a0.y + a1.y));
      uo[i] = fast_rcp(s);
    }

    // col partials over this thread's 8 rows only (no x32)
    float2 cs2[4] = {make_float2(0.f, 0.f), make_float2(0.f, 0.f),
                     make_float2(0.f, 0.f), make_float2(0.f, 0.f)};
#pragma unroll
    for (int i = 0; i < 8; ++i) {
      const float u = uo[i];
#pragma unroll
      for (int p = 0; p < 4; ++p)
        cs2[p] = make_float2(fmaf(la[i][p].x, u, cs2[p].x),
                             fmaf(la[i][p].y, u, cs2[p].y));
    }
#pragma unroll
    for (int p = 0; p < 4; ++p) {
      red[rbase + 32 * (2 * p)] = cs2[p].x;
      red[rbase + 32 * (2 * p + 1)] = cs2[p].y;
    }
    __syncthreads();

    {  // distributed sum-tree -> v = rcp(colsum)
      float v = red[q * RSTRIDE + slot];
#pragma unroll
      for (int m = 1; m < 8; ++m) v += red[(q + 4 * m) * RSTRIDE + slot];
      v += dpp_movf<0xB1>(v);
      v += dpp_movf<0x4E>(v);
      if (q == 0) colv[slot] = fast_rcp(v);
    }
    __syncthreads();

#pragma unroll
    for (int p = 0; p < 4; ++p)
      v2[p] = make_float2(colv[bc + 32 * (2 * p)],
                          colv[bc + 32 * (2 * p + 1)]);
    // next iteration's post-write __syncthreads protects colv/red hazards
  }

  // ---- output: out_ij = a_ij * u_i * v_j ----
  float4* o4 = (float4*)out + k * 16384;
#pragma unroll
  for (int i = 0; i < 8; ++i) {
    const int ridx = ((br << 3) + i) * 64 + (bc << 1);
    const float u = uo[i];
    float4 a, b;
    a.x = la[i][0].x * u * v2[0].x;
    a.y = la[i][0].y * u * v2[0].y;
    a.z = la[i][1].x * u * v2[1].x;
    a.w = la[i][1].y * u * v2[1].y;
    b.x = la[i][2].x * u * v2[2].x;
    b.y = la[i][2].y * u * v2[2].y;
    b.z = la[i][3].x * u * v2[3].x;
    b.w = la[i][3].y * u * v2[3].y;
    o4[ridx] = a;
    o4[ridx + 1] = b;
  }
}

extern "C" void kernel_launch(void* const* d_in, const int* in_sizes, int n_in,
                              void* d_out, int out_size, void* d_ws,
                              size_t ws_size, hipStream_t stream) {
  const float* plw = (const float*)d_in[0];
  const float* u = (const float*)d_in[1];
  const int* iters = (const int*)d_in[2];
  float* out = (float*)d_out;
  (void)in_sizes; (void)n_in; (void)out_size; (void)d_ws; (void)ws_size;
  lp_sinkhorn_kernel<<<dim3(KMAT), dim3(1024), 0, stream>>>(plw, u, iters, out);
}

// Round 8
// 86.248 us; speedup vs baseline: 1.4459x; 1.0588x over previous
//
#include <hip/hip_runtime.h>

// LearnPermutations: K=256 independent 256x256 Sinkhorn normalizations.
// One 1024-thread block per matrix; matrix register-resident, 8x8 tile/thread
// stored as ext_vector float2 (lowers to v_pk_*_f32 packed math on gfx950).
// Iteration 1 in log2 domain (huge 1/tau dynamic range), iterations 2..n as
// scaling-vector Sinkhorn u = rcp(A v), v = rcp(A^T u).
// R8: corrected b64 LDS layout (132-f2 row-group stride = verified 264-float
// padding), packed matvecs, verified hgroup_sum row reduction.

#define KMAT 256
#define RS2 132   // f2 stride per row-group (= 264 floats; bank rotate 8)
#define RSF 264   // float stride per row-group

typedef float f2 __attribute__((ext_vector_type(2)));
typedef unsigned uint2_ev __attribute__((ext_vector_type(2)));

__device__ __forceinline__ float fast_exp2(float x) {
#if __has_builtin(__builtin_amdgcn_exp2f)
  return __builtin_amdgcn_exp2f(x);
#else
  return exp2f(x);
#endif
}

__device__ __forceinline__ float fast_log2(float x) {
#if __has_builtin(__builtin_amdgcn_logf)
  return __builtin_amdgcn_logf(x);
#else
  return __log2f(x);
#endif
}

__device__ __forceinline__ float fast_rcp(float x) {
#if __has_builtin(__builtin_amdgcn_rcpf)
  return __builtin_amdgcn_rcpf(x);
#else
  return 1.0f / x;
#endif
}

__device__ __forceinline__ f2 f2fma(f2 a, f2 b, f2 c) {
#if __has_builtin(__builtin_elementwise_fma)
  return __builtin_elementwise_fma(a, b, c);
#else
  f2 r; r[0] = fmaf(a[0], b[0], c[0]); r[1] = fmaf(a[1], b[1], c[1]); return r;
#endif
}

template <int CTRL>
__device__ __forceinline__ float dpp_movf(float x) {
  return __int_as_float(
      __builtin_amdgcn_update_dpp(0, __float_as_int(x), CTRL, 0xf, 0xf, true));
}

__device__ __forceinline__ uint2_ev pl16_swap(unsigned a, unsigned b) {
  return __builtin_amdgcn_permlane16_swap(a, b, false, false);
}

// 32-lane half-group reductions (verified construction, R1-R6).
__device__ __forceinline__ float hgroup_max(float x) {
  x = fmaxf(x, dpp_movf<0x121>(x));
  x = fmaxf(x, dpp_movf<0x122>(x));
  x = fmaxf(x, dpp_movf<0x124>(x));
  x = fmaxf(x, dpp_movf<0x128>(x));
  uint2_ev r = pl16_swap(__float_as_uint(x), __float_as_uint(x));
  return fmaxf(__uint_as_float(r[0]), __uint_as_float(r[1]));
}

__device__ __forceinline__ float hgroup_sum(float x) {
  x += dpp_movf<0x121>(x);
  x += dpp_movf<0x122>(x);
  x += dpp_movf<0x124>(x);
  x += dpp_movf<0x128>(x);
  uint2_ev r = pl16_swap(__float_as_uint(x), __float_as_uint(x));
  return __uint_as_float(r[0]) + __uint_as_float(r[1]);
}

// Gumbel noise + temperature scaling, output in log2 domain.
__device__ __forceinline__ float gumbel_la(float p, float uv, float scale) {
  float lnu = fast_log2(uv + 1e-20f) * 0.69314718056f;
  float g = fast_log2(1e-20f - lnu) * (-0.0069314718056f);
  return (p + g) * scale;
}

__global__ __launch_bounds__(1024)
__attribute__((amdgpu_waves_per_eu(4, 4)))
void lp_sinkhorn_kernel(
    const float* __restrict__ plw, const float* __restrict__ uin,
    const int* __restrict__ itp, float* __restrict__ out) {
  const int k = blockIdx.x;
  const int t = threadIdx.x;
  const int br = t >> 5;   // 0..31 : half-wave row-group (8 rows each)
  const int bc = t & 31;   // 0..31 : col-group (8 cols each)
  const int wv = t >> 6;   // wave 0..15
  const int lane = t & 63;

  // Pair-slot layout: column pair (8bc+2p, 8bc+2p+1) at f2-slot 32p+bc of
  // each row-group. Row-group stride RS2=132 f2 (264 floats, bank rotate 8)
  // -> distributed tree's strided scalar reads are exactly 2-way (free).
  __shared__ f2 red2[32][RS2];
  __shared__ f2 colvp[128];
  float* redF = (float*)red2;    // row-group stride = RSF floats
  float* colv = (float*)colvp;   // 256 scalar col slots (slot = 64p+2bc+h)

  const int slot = 16 * wv + (lane >> 2);  // tree: scalar slot owned
  const int q = lane & 3;                  // tree: row-group quarter

  // ---- schedule parameters from `iterations` (uniform) ----
  double frac = (double)itp[0] * 1e-5;
  frac = frac < 0.0 ? 0.0 : (frac > 1.0 ? 1.0 : frac);
  const int n_iters = (int)(20.0 + frac * 130.0);
  const float tauf = (float)exp2((-3.0 - 4.0 * frac) * 3.3219280948873623);
  const float scale = (float)(1.4426950408889634 / (double)tauf);

  f2 la[8][4];

  // ---- load + gumbel + scale ----
  const float4* p4 = (const float4*)plw + k * 16384;
  const float4* u4 = (const float4*)uin + k * 16384;
#pragma unroll
  for (int i = 0; i < 8; ++i) {
    const int ridx = ((br << 3) + i) * 64 + (bc << 1);
    float4 p0 = p4[ridx];
    float4 p1 = p4[ridx + 1];
    float4 v0 = u4[ridx];
    float4 v1 = u4[ridx + 1];
    la[i][0] = f2{gumbel_la(p0.x, v0.x, scale), gumbel_la(p0.y, v0.y, scale)};
    la[i][1] = f2{gumbel_la(p0.z, v0.z, scale), gumbel_la(p0.w, v0.w, scale)};
    la[i][2] = f2{gumbel_la(p1.x, v1.x, scale), gumbel_la(p1.y, v1.y, scale)};
    la[i][3] = f2{gumbel_la(p1.z, v1.z, scale), gumbel_la(p1.w, v1.w, scale)};
  }

  // ======== iteration 1: LOG domain (row then col), ends linear ========
#pragma unroll
  for (int i = 0; i < 8; ++i) {
    float m = fmaxf(la[i][0][0], la[i][0][1]);
#pragma unroll
    for (int p = 1; p < 4; ++p) m = fmaxf(m, fmaxf(la[i][p][0], la[i][p][1]));
    m = hgroup_max(m);
    float s = 0.f;
#pragma unroll
    for (int p = 0; p < 4; ++p)
      s += fast_exp2(la[i][p][0] - m) + fast_exp2(la[i][p][1] - m);
    s = hgroup_sum(s);
    const float lse = m + fast_log2(s);
#pragma unroll
    for (int p = 0; p < 4; ++p) la[i][p] -= f2{lse, lse};
  }

  {  // col pass in log domain; convert to linear at the end
#pragma unroll
    for (int p = 0; p < 4; ++p) {
      f2 m = la[0][p];
#pragma unroll
      for (int i = 1; i < 8; ++i)
        m = f2{fmaxf(m[0], la[i][p][0]), fmaxf(m[1], la[i][p][1])};
      red2[br][32 * p + bc] = m;
    }
    __syncthreads();

    {  // distributed max tree (all 16 waves)
      float v = redF[q * RSF + slot];
#pragma unroll
      for (int m = 1; m < 8; ++m)
        v = fmaxf(v, redF[(q + 4 * m) * RSF + slot]);
      v = fmaxf(v, dpp_movf<0xB1>(v));  // quad_perm xor1
      v = fmaxf(v, dpp_movf<0x4E>(v));  // quad_perm xor2
      if (q == 0) colv[slot] = v;
    }
    __syncthreads();

    // exp partials vs global col max
#pragma unroll
    for (int p = 0; p < 4; ++p) {
      const f2 mj = colvp[32 * p + bc];
      f2 s = f2{0.f, 0.f};
#pragma unroll
      for (int i = 0; i < 8; ++i)
        s = f2{s[0] + fast_exp2(la[i][p][0] - mj[0]),
               s[1] + fast_exp2(la[i][p][1] - mj[1])};
      red2[br][32 * p + bc] = s;
    }
    __syncthreads();

    {  // distributed sum tree; lse = colmax + log2(sum)
      float v = redF[q * RSF + slot];
#pragma unroll
      for (int m = 1; m < 8; ++m) v += redF[(q + 4 * m) * RSF + slot];
      v += dpp_movf<0xB1>(v);
      v += dpp_movf<0x4E>(v);
      const float lse = colv[slot] + fast_log2(v);
      if (q == 0) colv[slot] = lse;
    }
    __syncthreads();

    // convert to linear: a = exp2(la - col_lse); colsums(a) == 1
#pragma unroll
    for (int p = 0; p < 4; ++p) {
      const f2 lse = colvp[32 * p + bc];
#pragma unroll
      for (int i = 0; i < 8; ++i)
        la[i][p] = f2{fast_exp2(la[i][p][0] - lse[0]),
                      fast_exp2(la[i][p][1] - lse[1])};
    }
  }

  // ======== iterations 2..n: scaling-vector Sinkhorn ========
  // u = rcp(A v); v = rcp(A^T u). Matrix registers read-only; all sums in
  // [1/256, 256] (colsums start at 1) -> rcp safe.
  float u[8] = {1.f, 1.f, 1.f, 1.f, 1.f, 1.f, 1.f, 1.f};
  f2 v2[4] = {f2{1.f, 1.f}, f2{1.f, 1.f}, f2{1.f, 1.f}, f2{1.f, 1.f}};

  for (int iter = 1; iter < n_iters; ++iter) {
    // ---- phase A: row dots (packed) + verified half-group reduce ----
#pragma unroll
    for (int i = 0; i < 8; ++i) {
      f2 a01 = la[i][0] * v2[0];
      a01 = f2fma(la[i][1], v2[1], a01);
      f2 a23 = la[i][2] * v2[2];
      a23 = f2fma(la[i][3], v2[3], a23);
      f2 acc = a01 + a23;
      u[i] = fast_rcp(hgroup_sum(acc[0] + acc[1]));
    }

    // ---- phase B: col partials (packed fma) ----
    f2 cs[4];
    {
      const f2 ub0 = f2{u[0], u[0]};
#pragma unroll
      for (int p = 0; p < 4; ++p) cs[p] = la[0][p] * ub0;
    }
#pragma unroll
    for (int i = 1; i < 8; ++i) {
      const f2 ub = f2{u[i], u[i]};
#pragma unroll
      for (int p = 0; p < 4; ++p) cs[p] = f2fma(la[i][p], ub, cs[p]);
    }
#pragma unroll
    for (int p = 0; p < 4; ++p) red2[br][32 * p + bc] = cs[p];
    __syncthreads();

    {  // distributed sum tree -> v = rcp(colsum)
      float v = redF[q * RSF + slot];
#pragma unroll
      for (int m = 1; m < 8; ++m) v += redF[(q + 4 * m) * RSF + slot];
      v += dpp_movf<0xB1>(v);
      v += dpp_movf<0x4E>(v);
      if (q == 0) colv[slot] = fast_rcp(v);
    }
    __syncthreads();

#pragma unroll
    for (int p = 0; p < 4; ++p) v2[p] = colvp[32 * p + bc];
    // next iteration's post-write __syncthreads protects colv/red2 hazards
  }

  // ---- output: out_ij = a_ij * u_i * v_j ----
  float4* o4 = (float4*)out + k * 16384;
#pragma unroll
  for (int i = 0; i < 8; ++i) {
    const int ridx = ((br << 3) + i) * 64 + (bc << 1);
    const f2 ub = f2{u[i], u[i]};
    f2 r0 = (la[i][0] * ub) * v2[0];
    f2 r1 = (la[i][1] * ub) * v2[1];
    f2 r2 = (la[i][2] * ub) * v2[2];
    f2 r3 = (la[i][3] * ub) * v2[3];
    float4 a, b;
    a.x = r0[0]; a.y = r0[1]; a.z = r1[0]; a.w = r1[1];
    b.x = r2[0]; b.y = r2[1]; b.z = r3[0]; b.w = r3[1];
    o4[ridx] = a;
    o4[ridx + 1] = b;
  }
}

extern "C" void kernel_launch(void* const* d_in, const int* in_sizes, int n_in,
                              void* d_out, int out_size, void* d_ws,
                              size_t ws_size, hipStream_t stream) {
  const float* plw = (const float*)d_in[0];
  const float* u = (const float*)d_in[1];
  const int* iters = (const int*)d_in[2];
  float* out = (float*)d_out;
  (void)in_sizes; (void)n_in; (void)out_size; (void)d_ws; (void)ws_size;
  lp_sinkhorn_kernel<<<dim3(KMAT), dim3(1024), 0, stream>>>(plw, u, iters, out);
}